// Round 5
// baseline (255.436 us; speedup 1.0000x reference)
//
#include <hip/hip_runtime.h>

#define N_PIX   32768
#define DIM     64
#define K_CODES 1024
#define NCHUNK  4
#define CHUNK   (K_CODES / NCHUNK)   // 256

// ws layout:
//   [0, 4096)                 : c2[1024] (float)
//   [4096, +1 MiB)            : partials float2[NCHUNK][N_PIX]
//   [4096 + 1 MiB, +128 KiB)  : idx[N_PIX] (int)

__global__ __launch_bounds__(256) void c2_kernel(const float* __restrict__ cb,
                                                 float* __restrict__ c2) {
    int k = blockIdx.x * 256 + threadIdx.x;
    if (k >= K_CODES) return;
    const float* row = cb + k * DIM;
    float a0 = 0.f, a1 = 0.f, a2 = 0.f, a3 = 0.f;
#pragma unroll
    for (int d = 0; d < DIM; d += 4) {
        a0 = fmaf(row[d + 0], row[d + 0], a0);
        a1 = fmaf(row[d + 1], row[d + 1], a1);
        a2 = fmaf(row[d + 2], row[d + 2], a2);
        a3 = fmaf(row[d + 3], row[d + 3], a3);
    }
    c2[k] = (a0 + a1) + (a2 + a3);
}

// One thread = one pixel; block = 256 pixels x 256 codes (64 KB LDS chunk).
// grid = 128 pixblk x 4 chunks = 512 blocks = exactly 2 blocks/CU.
// __launch_bounds__(256,2): 256-VGPR cap so x0..x15 (named float4s, asm-pinned)
// definitively live in VGPRs — rounds 2/4 showed the compiler re-loading x
// from global inside the k-loop (VGPR_Count 48/64, FETCH 33-35 MB).
__global__ __launch_bounds__(256, 2) void argmin_lds(const float* __restrict__ x,
                                                     const float* __restrict__ cb,
                                                     const float* __restrict__ c2,
                                                     float2* __restrict__ part) {
    __shared__ alignas(16) float4 lds_cb[CHUNK * (DIM / 4)];   // 64 KB
    __shared__ float lds_c2[CHUNK];                            // 1 KB

    int blk    = blockIdx.x;
    int pixblk = blk >> 2;       // 0..127
    int chunk  = blk & 3;        // 0..3
    int t  = threadIdx.x;
    int k0 = chunk * CHUNK;

    // Stage codebook chunk: 4096 float4s, 16 per thread, coalesced.
    {
        const float4* cb4 = reinterpret_cast<const float4*>(cb) + (size_t)k0 * (DIM / 4);
#pragma unroll
        for (int i = 0; i < 16; ++i)
            lds_cb[t + i * 256] = cb4[t + i * 256];
        lds_c2[t] = c2[k0 + t];   // CHUNK == blockDim
    }

    int p  = pixblk * 256 + t;   // pixel id
    int bb = p >> 10;            // batch
    int hw = p & 1023;           // h*32+w

    // x is [B, D, H, W]: element (bb, d, hw) at bb*65536 + d*1024 + hw.
    const float* xb = x + (size_t)bb * (DIM * 1024) + hw;
#define LDX(i) make_float4(xb[(size_t)(4*(i)+0) << 10], xb[(size_t)(4*(i)+1) << 10], \
                           xb[(size_t)(4*(i)+2) << 10], xb[(size_t)(4*(i)+3) << 10])
    float4 x0 = LDX(0),  x1 = LDX(1),  x2v = LDX(2),  x3 = LDX(3);
    float4 x4 = LDX(4),  x5 = LDX(5),  x6 = LDX(6),   x7 = LDX(7);
    float4 x8 = LDX(8),  x9 = LDX(9),  x10 = LDX(10), x11 = LDX(11);
    float4 x12 = LDX(12), x13 = LDX(13), x14 = LDX(14), x15 = LDX(15);
#undef LDX

    // x2 — identical reduction tree to the verified round-2/3 kernels:
    // s0..s3 accumulate d%4 == 0..3 in ascending d, then (s0+s1)+(s2+s3).
    float s0 = 0.f, s1 = 0.f, s2 = 0.f, s3 = 0.f;
#define SQ(v) { s0 = fmaf(v.x, v.x, s0); s1 = fmaf(v.y, v.y, s1); \
                s2 = fmaf(v.z, v.z, s2); s3 = fmaf(v.w, v.w, s3); }
    SQ(x0) SQ(x1) SQ(x2v) SQ(x3) SQ(x4) SQ(x5) SQ(x6) SQ(x7)
    SQ(x8) SQ(x9) SQ(x10) SQ(x11) SQ(x12) SQ(x13) SQ(x14) SQ(x15)
#undef SQ
    float x2 = (s0 + s1) + (s2 + s3);

    __syncthreads();

    // Pin the x fragments into VGPRs at this program point so the compiler
    // cannot rematerialize them as global reloads inside the k-loop.
#define PIN(v) asm volatile("" : "+v"(v.x), "+v"(v.y), "+v"(v.z), "+v"(v.w));
    PIN(x0) PIN(x1) PIN(x2v) PIN(x3) PIN(x4) PIN(x5) PIN(x6) PIN(x7)
    PIN(x8) PIN(x9) PIN(x10) PIN(x11) PIN(x12) PIN(x13) PIN(x14) PIN(x15)
#undef PIN

    float best = 1e30f;
    int   bidx = 0;
    for (int kk = 0; kk < CHUNK; ++kk) {
        const float4* wrow = &lds_cb[kk * (DIM / 4)];   // uniform addr -> broadcast
        float c2k = lds_c2[kk];
        float a0 = 0.f, a1 = 0.f, a2 = 0.f, a3 = 0.f;
#define STEP(i, xi) { float4 w = wrow[i]; \
        a0 = fmaf(xi.x, w.x, a0); a1 = fmaf(xi.y, w.y, a1); \
        a2 = fmaf(xi.z, w.z, a2); a3 = fmaf(xi.w, w.w, a3); }
        STEP(0, x0)  STEP(1, x1)  STEP(2, x2v)  STEP(3, x3)
        STEP(4, x4)  STEP(5, x5)  STEP(6, x6)   STEP(7, x7)
        STEP(8, x8)  STEP(9, x9)  STEP(10, x10) STEP(11, x11)
        STEP(12, x12) STEP(13, x13) STEP(14, x14) STEP(15, x15)
#undef STEP
        float dot = (a0 + a1) + (a2 + a3);
        // Reference rounding structure: d2 = (x2 - 2*dot) + c2 (ulp-64 grid
        // quantization stabilizes tie-breaking — verified exact, rounds 2-4).
        float u    = x2 - 2.0f * dot;   // fma contraction safe: 2*dot exact
        float dist = u + c2k;
        if (dist < best) { best = dist; bidx = k0 + kk; }  // strict <: first-min
    }
    float2 r;
    r.x = best;
    r.y = __int_as_float(bidx);
    part[(size_t)chunk * N_PIX + p] = r;   // coalesced
}

// Reduce the NCHUNK partials per pixel (ascending chunk, strict < = first-min),
// store idx, and write quantized [B, D, H, W]. grid = 256 blocks x 128.
__global__ __launch_bounds__(128) void reduce_quant(const float* __restrict__ cb,
                                                    const float2* __restrict__ part,
                                                    int* __restrict__ idx,
                                                    float* __restrict__ quant) {
    int n = blockIdx.x * 128 + threadIdx.x;
    float best = 1e30f;
    int   bi = 0;
#pragma unroll
    for (int c = 0; c < NCHUNK; ++c) {
        float2 r = part[(size_t)c * N_PIX + n];
        if (r.x < best) { best = r.x; bi = __float_as_int(r.y); }
    }
    idx[n] = bi;

    int bb = n >> 10;
    int hw = n & 1023;
    const float4* crow = reinterpret_cast<const float4*>(cb + (size_t)bi * DIM);
    float* qb = quant + (size_t)bb * (DIM * 1024) + hw;
#pragma unroll
    for (int dq = 0; dq < 16; ++dq) {
        float4 cv = crow[dq];            // L2-resident gather
        qb[(size_t)(dq * 4 + 0) << 10] = cv.x;   // consecutive hw lanes -> coalesced
        qb[(size_t)(dq * 4 + 1) << 10] = cv.y;
        qb[(size_t)(dq * 4 + 2) << 10] = cv.z;
        qb[(size_t)(dq * 4 + 3) << 10] = cv.w;
    }
}

// Streaming one-hot writer: flat float4 index e covers enc[n][j0..j0+3],
// n = e>>8, j0 = (e&255)*4. grid-stride, 2048 blocks.
__global__ __launch_bounds__(256) void enc_write(const int* __restrict__ idx,
                                                 float* __restrict__ enc) {
    const int TOT = (N_PIX / 4) * K_CODES;   // 8388608 float4s
    int tid = blockIdx.x * 256 + threadIdx.x;
    float4* enc4 = reinterpret_cast<float4*>(enc);
    for (int e = tid; e < TOT; e += 2048 * 256) {
        int n  = e >> 8;
        int j0 = (e & 255) << 2;
        int ir = idx[n];                 // row-uniform -> L1/L2 broadcast
        float4 v;
        v.x = (ir == j0 + 0) ? 1.0f : 0.0f;
        v.y = (ir == j0 + 1) ? 1.0f : 0.0f;
        v.z = (ir == j0 + 2) ? 1.0f : 0.0f;
        v.w = (ir == j0 + 3) ? 1.0f : 0.0f;
        enc4[e] = v;
    }
}

extern "C" void kernel_launch(void* const* d_in, const int* in_sizes, int n_in,
                              void* d_out, int out_size, void* d_ws, size_t ws_size,
                              hipStream_t stream) {
    const float* x  = (const float*)d_in[0];
    const float* cb = (const float*)d_in[1];

    float*  c2   = (float*)d_ws;
    float2* part = (float2*)((char*)d_ws + 4096);
    int*    idx  = (int*)((char*)d_ws + 4096 + (size_t)NCHUNK * N_PIX * 8);

    float* enc   = (float*)d_out;                           // [32768, 1024]
    float* quant = (float*)d_out + (size_t)N_PIX * K_CODES; // [32, 64, 32, 32]

    c2_kernel<<<K_CODES / 256, 256, 0, stream>>>(cb, c2);
    argmin_lds<<<(N_PIX / 256) * NCHUNK, 256, 0, stream>>>(x, cb, c2, part);
    reduce_quant<<<N_PIX / 128, 128, 0, stream>>>(cb, part, idx, quant);
    enc_write<<<2048, 256, 0, stream>>>(idx, enc);
}